// Round 1
// baseline (928.157 us; speedup 1.0000x reference)
//
#include <hip/hip_runtime.h>
#include <math.h>

#define E_TOTAL   1000000
#define HDIM      128
#define K1        256   // 2H
#define N1        512   // 4H
#define N2        128   // H
#define M_TILE    64
#define BLOCK     512
#define A_STRIDE  264   // 256 + 8 pad (f16): row stride 528B -> bank rotation, 2-way free
#define H1_STRIDE 520   // 512 + 8 pad
#define H2_STRIDE 136   // 128 + 8 pad

typedef _Float16 f16;
typedef _Float16 f16_4 __attribute__((ext_vector_type(4)));
typedef _Float16 f16_8 __attribute__((ext_vector_type(8)));
typedef float    f32_4 __attribute__((ext_vector_type(4)));

// Cast + transpose weights once per launch (cheap: 197k elements).
// W1 [256x512] f32 -> W1T f16 [n=512][k=256]; W2 [512x128] -> W2T f16 [n=128][k=512]
__global__ void prep_kernel(const float* __restrict__ W1, const float* __restrict__ W2,
                            f16* __restrict__ W1T, f16* __restrict__ W2T) {
    int t = blockIdx.x * blockDim.x + threadIdx.x;
    const int total1 = K1 * N1;
    const int total2 = N1 * N2;
    if (t < total1) {
        int k = t / N1, n = t - k * N1;
        W1T[n * K1 + k] = (f16)W1[t];
    } else if (t < total1 + total2) {
        int u = t - total1;
        int k = u / N2, n = u - k * N2;
        W2T[n * N1 + k] = (f16)W2[u];
    }
}

__global__ __launch_bounds__(BLOCK, 2) void edge_mlp_kernel(
    const float* __restrict__ emb,
    const int*   __restrict__ eidx,   // [2][E]: row0=col idx, row1=row idx
    const f16*   __restrict__ W1T,
    const float* __restrict__ b1,
    const f16*   __restrict__ W2T,
    const float* __restrict__ b2,
    const float* __restrict__ W3,
    const float* __restrict__ b3,
    float* __restrict__ out)
{
    __shared__ __align__(16) f16 sA[M_TILE * A_STRIDE];     // gathered [64][256] f16; reused as H2
    __shared__ __align__(16) f16 sH1[M_TILE * H1_STRIDE];   // [64][512] f16
    f16* sH2 = sA;                                          // [64][128] f16, overlaps sA

    const int tid = threadIdx.x;
    const int e0  = blockIdx.x * M_TILE;   // E_TOTAL % M_TILE == 0, no guards needed

    // ---- Phase 0: gather emb[col]||emb[row] -> sA (f16) ----
    {
        const int half = tid >> 2;     // 0..127 : edge-half
        const int sub  = tid & 3;      // 4 threads per half, 8 float4 each
        const int m    = half >> 1;
        const int side = half & 1;     // 0 = col (first 128), 1 = row (second 128)
        const int node = eidx[side * E_TOTAL + e0 + m];
        const float4* src = (const float4*)(emb + (size_t)node * HDIM);
        f16* dst = sA + m * A_STRIDE + side * HDIM;
        #pragma unroll
        for (int i = 0; i < 8; ++i) {
            const int c4 = sub + 4 * i;
            float4 f = src[c4];
            f16_4 v = { (f16)f.x, (f16)f.y, (f16)f.z, (f16)f.w };
            *(f16_4*)(dst + c4 * 4) = v;
        }
    }
    __syncthreads();

    const int wave = tid >> 6;     // 8 waves
    const int lane = tid & 63;
    const int lrow = lane & 15;    // MFMA: m (A) / n (B) / col (C)
    const int quad = lane >> 4;    // MFMA: k-group (A/B) / row-group (C)

    // ---- Phase 1: H1 = relu(A @ W1 + b1)   M=64 K=256 N=512 ----
    // wave handles N-strip [wave*64, wave*64+64), 4 n-tiles x 4 m-tiles
    {
        #pragma unroll
        for (int nt = 0; nt < 4; ++nt) {
            const int n = wave * 64 + nt * 16 + lrow;
            f32_4 acc[4];
            #pragma unroll
            for (int mt = 0; mt < 4; ++mt) acc[mt] = (f32_4){0.f, 0.f, 0.f, 0.f};
            const f16* wptr = W1T + n * K1 + quad * 8;            // B[k][n]: k = ks*32+quad*8+j
            const f16* aptr = sA + lrow * A_STRIDE + quad * 8;    // A[m][k]
            #pragma unroll
            for (int ks = 0; ks < 8; ++ks) {
                f16_8 bfrag = *(const f16_8*)(wptr + ks * 32);
                #pragma unroll
                for (int mt = 0; mt < 4; ++mt) {
                    f16_8 afrag = *(const f16_8*)(aptr + ks * 32 + mt * 16 * A_STRIDE);
                    acc[mt] = __builtin_amdgcn_mfma_f32_16x16x32_f16(afrag, bfrag, acc[mt], 0, 0, 0);
                }
            }
            const float bias = b1[n];
            #pragma unroll
            for (int mt = 0; mt < 4; ++mt) {
                #pragma unroll
                for (int i = 0; i < 4; ++i) {
                    const int m = mt * 16 + quad * 4 + i;   // C/D: col=lane&15, row=quad*4+reg
                    float v = acc[mt][i] + bias;
                    v = v > 0.0f ? v : 0.0f;
                    sH1[m * H1_STRIDE + n] = (f16)v;
                }
            }
        }
    }
    __syncthreads();

    // ---- Phase 2: H2 = relu(H1 @ W2 + b2)   M=64 K=512 N=128 ----
    // wave handles N-strip [wave*16, wave*16+16)
    {
        const int n = wave * 16 + lrow;
        f32_4 acc[4];
        #pragma unroll
        for (int mt = 0; mt < 4; ++mt) acc[mt] = (f32_4){0.f, 0.f, 0.f, 0.f};
        const f16* wptr = W2T + n * N1 + quad * 8;
        const f16* aptr = sH1 + lrow * H1_STRIDE + quad * 8;
        #pragma unroll
        for (int ks = 0; ks < 16; ++ks) {
            f16_8 bfrag = *(const f16_8*)(wptr + ks * 32);
            #pragma unroll
            for (int mt = 0; mt < 4; ++mt) {
                f16_8 afrag = *(const f16_8*)(aptr + ks * 32 + mt * 16 * H1_STRIDE);
                acc[mt] = __builtin_amdgcn_mfma_f32_16x16x32_f16(afrag, bfrag, acc[mt], 0, 0, 0);
            }
        }
        const float bias = b2[n];
        #pragma unroll
        for (int mt = 0; mt < 4; ++mt) {
            #pragma unroll
            for (int i = 0; i < 4; ++i) {
                const int m = mt * 16 + quad * 4 + i;
                float v = acc[mt][i] + bias;
                v = v > 0.0f ? v : 0.0f;
                sH2[m * H2_STRIDE + n] = (f16)v;   // safe: sA reads all completed before phase-2 sync
            }
        }
    }
    __syncthreads();

    // ---- Phase 3: logit = H2 @ W3 + b3 ; out = sigmoid(logit) ----
    {
        const int m = tid >> 3;    // 8 threads per edge, 16 elems each
        const int j = tid & 7;
        const f16* hrow = sH2 + m * H2_STRIDE + j * 16;
        float s = 0.0f;
        #pragma unroll
        for (int c = 0; c < 16; ++c)
            s += (float)hrow[c] * W3[j * 16 + c];
        s += __shfl_xor(s, 1);
        s += __shfl_xor(s, 2);
        s += __shfl_xor(s, 4);
        if (j == 0) {
            const float logit = s + b3[0];
            out[e0 + m] = 1.0f / (1.0f + __expf(-logit));
        }
    }
}

extern "C" void kernel_launch(void* const* d_in, const int* in_sizes, int n_in,
                              void* d_out, int out_size, void* d_ws, size_t ws_size,
                              hipStream_t stream) {
    const float* emb  = (const float*)d_in[0];
    const int*   eidx = (const int*)d_in[1];
    const float* W1   = (const float*)d_in[2];
    const float* b1   = (const float*)d_in[3];
    const float* W2   = (const float*)d_in[4];
    const float* b2   = (const float*)d_in[5];
    const float* W3   = (const float*)d_in[6];
    const float* b3   = (const float*)d_in[7];
    float* out = (float*)d_out;

    f16* W1T = (f16*)d_ws;                 // 512*256*2 = 256 KB
    f16* W2T = W1T + K1 * N1;              // 128*512*2 = 128 KB

    const int prep_total = K1 * N1 + N1 * N2;
    prep_kernel<<<(prep_total + 255) / 256, 256, 0, stream>>>(W1, W2, W1T, W2T);

    edge_mlp_kernel<<<E_TOTAL / M_TILE, BLOCK, 0, stream>>>(
        emb, eidx, W1T, b1, W2T, b2, W3, b3, out);
}

// Round 2
// 688.378 us; speedup vs baseline: 1.3483x; 1.3483x over previous
//
#include <hip/hip_runtime.h>
#include <math.h>

#define E_TOTAL   1000000
#define HDIM      128
#define K1        256   // 2H
#define N1        512   // 4H
#define N2        128   // H
#define M_TILE    64
#define BLOCK     512

typedef _Float16 f16;
typedef _Float16 f16_4 __attribute__((ext_vector_type(4)));
typedef _Float16 f16_8 __attribute__((ext_vector_type(8)));
typedef float    f32_4 __attribute__((ext_vector_type(4)));

// Fragment-packed weights so wave loads are contiguous 1KB:
// W1F[tile(32)][ks(8)][lane(64)][v(8)] = W1[k=ks*32+(lane>>4)*8+v][n=tile*16+(lane&15)]
// W2F[tile(8)][kc(16)][lane(64)][v(8)] = W2[k=kc*32+(lane>>4)*8+v][n=tile*16+(lane&15)]
__global__ void prep_kernel(const float* __restrict__ W1, const float* __restrict__ W2,
                            f16* __restrict__ W1F, f16* __restrict__ W2F) {
    int t = blockIdx.x * blockDim.x + threadIdx.x;
    const int total1 = K1 * N1;           // 131072
    const int total2 = N1 * N2;           // 65536
    if (t < total1) {
        int v    = t & 7;
        int lane = (t >> 3) & 63;
        int ks   = (t >> 9) & 7;
        int tile = t >> 12;
        int n = tile * 16 + (lane & 15);
        int k = ks * 32 + (lane >> 4) * 8 + v;
        W1F[t] = (f16)W1[k * N1 + n];
    } else if (t < total1 + total2) {
        int u = t - total1;
        int v    = u & 7;
        int lane = (u >> 3) & 63;
        int kc   = (u >> 9) & 15;
        int tile = u >> 13;
        int n = tile * 16 + (lane & 15);
        int k = kc * 32 + (lane >> 4) * 8 + v;
        W2F[u] = (f16)W2[k * N2 + n];
    }
}

// XOR-swizzled LDS, 16B chunk granularity: element (row, chunk) stored at chunk^(row&7).
// sA  : [64 edges][256 k]  f16 = 32 KB   (reused as sH2 [64][128] = 16 KB)
// sH1 : [64 edges][256 wn] f16 = 32 KB   (one 256-wide half of H1 at a time)
__global__ __launch_bounds__(BLOCK, 4) void edge_mlp_kernel(
    const float* __restrict__ emb,
    const int*   __restrict__ eidx,
    const f16*   __restrict__ W1F,
    const float* __restrict__ b1,
    const f16*   __restrict__ W2F,
    const float* __restrict__ b2,
    const float* __restrict__ W3,
    const float* __restrict__ b3,
    float* __restrict__ out)
{
    __shared__ __align__(16) f16 sA[M_TILE * 256];
    __shared__ __align__(16) f16 sH1[M_TILE * 256];
    f16* sH2 = sA;  // [64][128], valid after final phase-1 half has consumed sA

    const int tid = threadIdx.x;
    const int e0  = blockIdx.x * M_TILE;

    // ---- Phase 0: gather emb[col]||emb[row] -> sA (f16, swizzled) ----
    {
        const int m    = tid >> 3;          // edge 0..63
        const int side = (tid >> 2) & 1;    // 0: first 128 cols, 1: second
        const int sub  = tid & 3;
        const int node = eidx[side * E_TOTAL + e0 + m];
        const float4* src = (const float4*)(emb + (size_t)node * HDIM);
        #pragma unroll
        for (int i = 0; i < 8; ++i) {
            const int c4 = sub + 4 * i;               // float4 index within 128
            float4 f = src[c4];
            f16_4 v = { (f16)f.x, (f16)f.y, (f16)f.z, (f16)f.w };
            const int ch  = side * 16 + (c4 >> 1);    // true 16B chunk
            const int off = (c4 & 1) * 4;
            *(f16_4*)(sA + m * 256 + (((ch ^ (m & 7)) << 3) + off)) = v;
        }
    }
    __syncthreads();

    const int wv   = tid >> 6;   // wave 0..7
    const int lane = tid & 63;
    const int lrow = lane & 15;
    const int quad = lane >> 4;

    f32_4 acc2[4];               // phase-2 accumulators, persist across both halves
    #pragma unroll
    for (int et = 0; et < 4; ++et) acc2[et] = (f32_4){0.f, 0.f, 0.f, 0.f};

    #pragma unroll
    for (int h = 0; h < 2; ++h) {
        // ---- Phase 1 (half h): H1[:, h*256 + wv*32 .. +32] = relu(A @ W1 + b1)
        // wave tile: 64 edges x 32 wn  (4 et x 2 wnt); each edge-frag feeds 8 MFMAs
        {
            f32_4 acc1[2][4];
            #pragma unroll
            for (int wnt = 0; wnt < 2; ++wnt)
                #pragma unroll
                for (int et = 0; et < 4; ++et) acc1[wnt][et] = (f32_4){0.f, 0.f, 0.f, 0.f};

            #pragma unroll
            for (int ks = 0; ks < 8; ++ks) {
                const int c = ks * 4 + quad;
                f16_8 ef[4];
                #pragma unroll
                for (int et = 0; et < 4; ++et) {
                    const int row = et * 16 + lrow;
                    ef[et] = *(const f16_8*)(sA + row * 256 + ((c ^ (row & 7)) << 3));
                }
                #pragma unroll
                for (int wnt = 0; wnt < 2; ++wnt) {
                    const int tile = h * 16 + wv * 2 + wnt;
                    f16_8 wf = *(const f16_8*)(W1F + (((tile * 8 + ks) * 64 + lane) << 3));
                    #pragma unroll
                    for (int et = 0; et < 4; ++et)
                        acc1[wnt][et] = __builtin_amdgcn_mfma_f32_16x16x32_f16(wf, ef[et], acc1[wnt][et], 0, 0, 0);
                }
            }
            // epilogue: lane holds H1[edge=et*16+lrow][wn=base+quad*4+i] -> b64 writes
            #pragma unroll
            for (int wnt = 0; wnt < 2; ++wnt) {
                const float4 bias = *(const float4*)(b1 + h * 256 + wv * 32 + wnt * 16 + quad * 4);
                const int klocal = wv * 32 + wnt * 16 + quad * 4;   // wn within half
                const int ch  = klocal >> 3;
                const int off = klocal & 7;
                #pragma unroll
                for (int et = 0; et < 4; ++et) {
                    const int row = et * 16 + lrow;
                    f16_4 hv;
                    #pragma unroll
                    for (int i = 0; i < 4; ++i) {
                        float v = acc1[wnt][et][i] + ((const float*)&bias)[i];
                        hv[i] = (f16)(v > 0.f ? v : 0.f);
                    }
                    *(f16_4*)(sH1 + row * 256 + (((ch ^ (row & 7)) << 3) + off)) = hv;
                }
            }
        }
        __syncthreads();   // sH1 half ready

        // ---- Phase 2 (half h): acc2 += H1half @ W2[h*256.., :]
        // wave tile: 64 edges x 16 wn (wn = wv*16..)
        #pragma unroll
        for (int ks = 0; ks < 8; ++ks) {
            const int c = ks * 4 + quad;
            f16_8 ef[4];
            #pragma unroll
            for (int et = 0; et < 4; ++et) {
                const int row = et * 16 + lrow;
                ef[et] = *(const f16_8*)(sH1 + row * 256 + ((c ^ (row & 7)) << 3));
            }
            f16_8 wf = *(const f16_8*)(W2F + (((wv * 16 + h * 8 + ks) * 64 + lane) << 3));
            #pragma unroll
            for (int et = 0; et < 4; ++et)
                acc2[et] = __builtin_amdgcn_mfma_f32_16x16x32_f16(wf, ef[et], acc2[et], 0, 0, 0);
        }
        __syncthreads();   // done reading sH1 half (next h overwrites it)
    }

    // ---- Phase 2 epilogue: sH2[edge][wn] (overlays sA; all sA reads done) ----
    {
        const float4 b2v = *(const float4*)(b2 + wv * 16 + quad * 4);
        const int wn  = wv * 16 + quad * 4;
        const int ch  = wn >> 3;
        const int off = wn & 7;
        #pragma unroll
        for (int et = 0; et < 4; ++et) {
            const int row = et * 16 + lrow;
            f16_4 hv;
            #pragma unroll
            for (int i = 0; i < 4; ++i) {
                float v = acc2[et][i] + ((const float*)&b2v)[i];
                hv[i] = (f16)(v > 0.f ? v : 0.f);
            }
            *(f16_4*)(sH2 + row * 128 + (((ch ^ (row & 7)) << 3) + off)) = hv;
        }
    }
    __syncthreads();

    // ---- Phase 3: logit = H2 @ W3 + b3 ; sigmoid ----
    {
        const int m = tid >> 3;   // edge
        const int j = tid & 7;    // 16-k slice
        const int c0 = (2 * j)     ^ (m & 7);
        const int c1 = (2 * j + 1) ^ (m & 7);
        f16_8 a = *(const f16_8*)(sH2 + m * 128 + (c0 << 3));
        f16_8 b = *(const f16_8*)(sH2 + m * 128 + (c1 << 3));
        const float* w3p = W3 + j * 16;
        float s = 0.f;
        #pragma unroll
        for (int t = 0; t < 8; ++t) s += (float)a[t] * w3p[t];
        #pragma unroll
        for (int t = 0; t < 8; ++t) s += (float)b[t] * w3p[8 + t];
        s += __shfl_xor(s, 1);
        s += __shfl_xor(s, 2);
        s += __shfl_xor(s, 4);
        if (j == 0) {
            const float logit = s + b3[0];
            out[e0 + m] = 1.0f / (1.0f + __expf(-logit));
        }
    }
}

extern "C" void kernel_launch(void* const* d_in, const int* in_sizes, int n_in,
                              void* d_out, int out_size, void* d_ws, size_t ws_size,
                              hipStream_t stream) {
    const float* emb  = (const float*)d_in[0];
    const int*   eidx = (const int*)d_in[1];
    const float* W1   = (const float*)d_in[2];
    const float* b1   = (const float*)d_in[3];
    const float* W2   = (const float*)d_in[4];
    const float* b2   = (const float*)d_in[5];
    const float* W3   = (const float*)d_in[6];
    const float* b3   = (const float*)d_in[7];
    float* out = (float*)d_out;

    f16* W1F = (f16*)d_ws;                 // 256 KB
    f16* W2F = W1F + K1 * N1;              // 128 KB

    const int prep_total = K1 * N1 + N1 * N2;
    prep_kernel<<<(prep_total + 255) / 256, 256, 0, stream>>>(W1, W2, W1F, W2F);

    edge_mlp_kernel<<<E_TOTAL / M_TILE, BLOCK, 0, stream>>>(
        emb, eidx, W1F, b1, W2F, b2, W3, b3, out);
}

// Round 3
// 683.377 us; speedup vs baseline: 1.3582x; 1.0073x over previous
//
#include <hip/hip_runtime.h>
#include <math.h>

#define E_TOTAL   1000000
#define HDIM      128
#define K1        256   // 2H
#define N1        512   // 4H
#define N2        128   // H
#define M_TILE    64
#define BLOCK     512

typedef _Float16 f16;
typedef _Float16 f16_4  __attribute__((ext_vector_type(4)));
typedef _Float16 f16_8  __attribute__((ext_vector_type(8)));
typedef float    f32_16 __attribute__((ext_vector_type(16)));

// ---------------- prep kernels ----------------
// 32x32x16 fragment packing:
// A/B frag layout: lane l holds elem [row=l&31][k=(l>>5)*8+v], v=0..7
// W1F[nt(16)][kc(16)][lane(64)][v(8)] = W1[k=kc*16+(l>>5)*8+v][n=nt*32+(l&31)]
// W2F[nt(4)][kcg(32)][lane(64)][v(8)] = W2[k=kcg*16+(l>>5)*8+v][n=nt*32+(l&31)]
__global__ void prep_weights(const float* __restrict__ W1, const float* __restrict__ W2,
                             f16* __restrict__ W1F, f16* __restrict__ W2F) {
    int t = blockIdx.x * blockDim.x + threadIdx.x;
    const int total1 = K1 * N1;           // 131072
    const int total2 = N1 * N2;           // 65536
    if (t < total1) {
        int v    = t & 7;
        int lane = (t >> 3) & 63;
        int kc   = (t >> 9) & 15;
        int nt   = t >> 13;
        int k = kc * 16 + (lane >> 5) * 8 + v;
        int n = nt * 32 + (lane & 31);
        W1F[t] = (f16)W1[k * N1 + n];
    } else if (t < total1 + total2) {
        int u = t - total1;
        int v    = u & 7;
        int lane = (u >> 3) & 63;
        int kcg  = (u >> 9) & 31;
        int nt   = u >> 14;
        int k = kcg * 16 + (lane >> 5) * 8 + v;
        int n = nt * 32 + (lane & 31);
        W2F[u] = (f16)W2[k * N2 + n];
    }
}

__global__ void prep_emb(const float* __restrict__ emb, f16* __restrict__ emb16) {
    int t = blockIdx.x * blockDim.x + threadIdx.x;   // 3.2M threads, 4 elems each
    float4 f = ((const float4*)emb)[t];
    f16_4 v = { (f16)f.x, (f16)f.y, (f16)f.z, (f16)f.w };
    ((f16_4*)emb16)[t] = v;
}

// ---------------- main kernel ----------------
// LDS (XOR-swizzled at 16B chunks: physical chunk = logical ^ (row&7)):
//   sA  [64 edges][256 k] f16 = 32 KB  (reused as sH2 [64][128] after P1h1)
//   sH1 [64 edges][256 wn] f16 = 32 KB (one 256-wide N-half of H1 at a time)
// Waves: 8 = 2 et(32 edges) x 4 ntg. 32x32x16 MFMA: ef feeds 2 MFMAs (P1).
template <bool F16EMB>
__global__ __launch_bounds__(BLOCK, 4) void edge_mlp_kernel(
    const float* __restrict__ emb,
    const f16*   __restrict__ emb16,
    const int*   __restrict__ eidx,
    const f16*   __restrict__ W1F,
    const float* __restrict__ b1,
    const f16*   __restrict__ W2F,
    const float* __restrict__ b2,
    const float* __restrict__ W3,
    const float* __restrict__ b3,
    float* __restrict__ out)
{
    __shared__ __align__(16) f16 sA[M_TILE * 256];
    __shared__ __align__(16) f16 sH1[M_TILE * 256];
    f16* sH2 = sA;

    const int tid = threadIdx.x;
    const int e0  = blockIdx.x * M_TILE;

    // ---- Phase 0: gather emb[col]||emb[row] -> sA (f16, swizzled) ----
    if (F16EMB) {
        const int row  = tid >> 2;        // 0..127 node-slot
        const int g    = tid & 3;         // 64B piece within 256B row
        const int m    = row >> 1;
        const int side = row & 1;
        const int node = eidx[side * E_TOTAL + e0 + m];
        const f16_8* src = (const f16_8*)(emb16 + (size_t)node * HDIM + g * 32);
        #pragma unroll
        for (int i = 0; i < 4; ++i) {
            f16_8 v = src[i];
            const int ch = side * 16 + g * 4 + i;
            *(f16_8*)(sA + m * 256 + ((ch ^ (m & 7)) << 3)) = v;
        }
    } else {
        const int m    = tid >> 3;
        const int side = (tid >> 2) & 1;
        const int sub  = tid & 3;
        const int node = eidx[side * E_TOTAL + e0 + m];
        const float4* src = (const float4*)(emb + (size_t)node * HDIM);
        #pragma unroll
        for (int i = 0; i < 8; ++i) {
            const int c4 = sub + 4 * i;
            float4 f = src[c4];
            f16_4 v = { (f16)f.x, (f16)f.y, (f16)f.z, (f16)f.w };
            const int ch  = side * 16 + (c4 >> 1);
            const int off = (c4 & 1) * 4;
            *(f16_4*)(sA + m * 256 + (((ch ^ (m & 7)) << 3) + off)) = v;
        }
    }
    __syncthreads();

    const int wv   = tid >> 6;     // 0..7
    const int lane = tid & 63;
    const int l31  = lane & 31;
    const int lh   = lane >> 5;    // 0/1
    const int et   = wv & 1;       // edge tile (32 edges)
    const int ntg  = wv >> 1;      // 0..3
    const int arow = et * 32 + l31;            // A-frag row (edge)
    const int asw  = arow & 7;

    f32_16 acc2 = {0.f};   // P2 accumulator, carried across both K-halves

    #pragma unroll
    for (int hh = 0; hh < 2; ++hh) {
        // ---- Phase 1 (half hh): H1[:, hh*256 + ntg*64 .. ] ----
        {
            f32_16 acc1[2] = {{0.f}, {0.f}};
            #pragma unroll
            for (int kc = 0; kc < 16; ++kc) {
                const int ch = kc * 2 + lh;
                f16_8 ef = *(const f16_8*)(sA + arow * 256 + ((ch ^ asw) << 3));
                #pragma unroll
                for (int j = 0; j < 2; ++j) {
                    const int nt = hh * 8 + ntg * 2 + j;   // global n-tile
                    f16_8 wf = *(const f16_8*)(W1F + (((nt * 16 + kc) * 64 + lane) << 3));
                    acc1[j] = __builtin_amdgcn_mfma_f32_32x32x16_f16(wf, ef, acc1[j], 0, 0, 0);
                }
            }
            // epilogue: lane holds D[wn=4*lh+8*g+i][edge=arow] -> f16_4 (b64) writes
            #pragma unroll
            for (int j = 0; j < 2; ++j) {
                const int nth = ntg * 2 + j;               // tile within half
                #pragma unroll
                for (int g = 0; g < 4; ++g) {
                    const int wnh = nth * 32 + lh * 4 + g * 8;   // wn within half
                    const float4 bv = *(const float4*)(b1 + hh * 256 + wnh);
                    f16_4 hv;
                    #pragma unroll
                    for (int i = 0; i < 4; ++i) {
                        float v = acc1[j][g * 4 + i] + ((const float*)&bv)[i];
                        hv[i] = (f16)(v > 0.f ? v : 0.f);
                    }
                    const int ch  = wnh >> 3;
                    const int off = wnh & 7;               // = lh*4, 8B aligned
                    *(f16_4*)(sH1 + arow * 256 + (((ch ^ asw) << 3) + off)) = hv;
                }
            }
        }
        __syncthreads();   // sH1 half ready

        // ---- Phase 2 (half hh): acc2 += H1half @ W2[hh*256.., nt2*32..] ----
        {
            const int nt2 = ntg;   // 0..3 covers wn 0..127
            #pragma unroll
            for (int kc = 0; kc < 16; ++kc) {
                const int ch = kc * 2 + lh;
                f16_8 ef = *(const f16_8*)(sH1 + arow * 256 + ((ch ^ asw) << 3));
                f16_8 wf = *(const f16_8*)(W2F + (((nt2 * 32 + hh * 16 + kc) * 64 + lane) << 3));
                acc2 = __builtin_amdgcn_mfma_f32_32x32x16_f16(wf, ef, acc2, 0, 0, 0);
            }
        }
        __syncthreads();   // done reading sH1 half (next hh overwrites it)
    }

    // ---- Phase 2 epilogue -> sH2 [64][128] (overlays sA; all sA reads done) ----
    {
        const int nt2 = ntg;
        #pragma unroll
        for (int g = 0; g < 4; ++g) {
            const int wn = nt2 * 32 + lh * 4 + g * 8;
            const float4 bv = *(const float4*)(b2 + wn);
            f16_4 hv;
            #pragma unroll
            for (int i = 0; i < 4; ++i) {
                float v = acc2[g * 4 + i] + ((const float*)&bv)[i];
                hv[i] = (f16)(v > 0.f ? v : 0.f);
            }
            const int ch  = wn >> 3;
            const int off = wn & 7;
            *(f16_4*)(sH2 + arow * 128 + (((ch ^ asw) << 3) + off)) = hv;
        }
    }
    __syncthreads();

    // ---- Phase 3: logit = H2 @ W3 + b3 ; sigmoid ----
    {
        const int m = tid >> 3;   // edge
        const int j = tid & 7;    // 16-k slice
        const int c0 = (2 * j)     ^ (m & 7);
        const int c1 = (2 * j + 1) ^ (m & 7);
        f16_8 a = *(const f16_8*)(sH2 + m * 128 + (c0 << 3));
        f16_8 b = *(const f16_8*)(sH2 + m * 128 + (c1 << 3));
        const float4* w3v = (const float4*)(W3 + j * 16);
        float4 w0 = w3v[0], w1 = w3v[1], w2 = w3v[2], w3 = w3v[3];
        float s = 0.f;
        s += (float)a[0]*w0.x + (float)a[1]*w0.y + (float)a[2]*w0.z + (float)a[3]*w0.w;
        s += (float)a[4]*w1.x + (float)a[5]*w1.y + (float)a[6]*w1.z + (float)a[7]*w1.w;
        s += (float)b[0]*w2.x + (float)b[1]*w2.y + (float)b[2]*w2.z + (float)b[3]*w2.w;
        s += (float)b[4]*w3.x + (float)b[5]*w3.y + (float)b[6]*w3.z + (float)b[7]*w3.w;
        s += __shfl_xor(s, 1);
        s += __shfl_xor(s, 2);
        s += __shfl_xor(s, 4);
        if (j == 0) {
            const float logit = s + b3[0];
            out[e0 + m] = 1.0f / (1.0f + __expf(-logit));
        }
    }
}

extern "C" void kernel_launch(void* const* d_in, const int* in_sizes, int n_in,
                              void* d_out, int out_size, void* d_ws, size_t ws_size,
                              hipStream_t stream) {
    const float* emb  = (const float*)d_in[0];
    const int*   eidx = (const int*)d_in[1];
    const float* W1   = (const float*)d_in[2];
    const float* b1   = (const float*)d_in[3];
    const float* W2   = (const float*)d_in[4];
    const float* b2   = (const float*)d_in[5];
    const float* W3   = (const float*)d_in[6];
    const float* b3   = (const float*)d_in[7];
    float* out = (float*)d_out;

    const size_t wbytes   = (size_t)(K1 * N1 + N1 * N2) * sizeof(f16);   // 384 KB
    const size_t embbytes = (size_t)100000 * HDIM * sizeof(f16);         // 25.6 MB

    f16* W1F = (f16*)d_ws;
    f16* W2F = W1F + K1 * N1;

    const int prep_total = K1 * N1 + N1 * N2;
    prep_weights<<<(prep_total + 255) / 256, 256, 0, stream>>>(W1, W2, W1F, W2F);

    if (ws_size >= wbytes + embbytes) {
        f16* emb16 = W2F + N1 * N2;
        const int cvt_threads = 100000 * HDIM / 4;   // 3.2M
        prep_emb<<<cvt_threads / 256, 256, 0, stream>>>(emb, emb16);
        edge_mlp_kernel<true><<<E_TOTAL / M_TILE, BLOCK, 0, stream>>>(
            emb, emb16, eidx, W1F, b1, W2F, b2, W3, b3, out);
    } else {
        edge_mlp_kernel<false><<<E_TOTAL / M_TILE, BLOCK, 0, stream>>>(
            emb, (const f16*)nullptr, eidx, W1F, b1, W2F, b2, W3, b3, out);
    }
}